// Round 1
// baseline (156.882 us; speedup 1.0000x reference)
//
#include <hip/hip_runtime.h>
#include <math.h>

// Problem constants
constexpr int B = 4, S = 4096, N = 16, D = 64, M = 4;
constexpr int SND = S * N * D;      // 4,194,304 (b stride for q/k/v)
constexpr int ND  = N * D;          // 1024 (s stride)
constexpr int DD  = D * D;          // 4096

// ---------------------------------------------------------------------------
// Kernel 1: partial outer-product accumulation
//   part[bn][chunk][k][v] = sum_{s in chunk} k[b,s,n,k] * v[b,s,n,v]
// grid = (64, nchunks), block = 256
// ---------------------------------------------------------------------------
__global__ __launch_bounds__(256) void k1_partials(const float* __restrict__ kg,
                                                   const float* __restrict__ vg,
                                                   float* __restrict__ part,
                                                   int spb) {
  __shared__ __align__(16) float kb[16 * 68];
  __shared__ __align__(16) float vb[16 * 68];

  const int t = threadIdx.x;
  const int bn = blockIdx.x;
  const int b = bn >> 4, n = bn & 15;
  const size_t base = (size_t)b * SND + (size_t)n * D;
  const int s0 = blockIdx.y * spb;

  const int row = t >> 4;          // 0..15  (staging row)
  const int d4  = (t & 15) * 4;    // 0..60  (staging col, float4)
  const int k0  = (t >> 4) * 4;    // compute tile: k rows
  const int v0  = (t & 15) * 4;    // compute tile: v cols

  float acc[4][4] = {};

  for (int sb = 0; sb < spb; sb += 16) {
    const size_t srow = base + (size_t)(s0 + sb + row) * ND + d4;
    const float4 kl = *(const float4*)(kg + srow);
    const float4 vl = *(const float4*)(vg + srow);
    *(float4*)&kb[row * 68 + d4] = kl;
    *(float4*)&vb[row * 68 + d4] = vl;
    __syncthreads();
#pragma unroll
    for (int ss = 0; ss < 16; ++ss) {
      const float4 kk4 = *(const float4*)&kb[ss * 68 + k0];
      const float4 vv4 = *(const float4*)&vb[ss * 68 + v0];
      const float ka[4] = {kk4.x, kk4.y, kk4.z, kk4.w};
      const float va[4] = {vv4.x, vv4.y, vv4.z, vv4.w};
#pragma unroll
      for (int i = 0; i < 4; ++i)
#pragma unroll
        for (int j = 0; j < 4; ++j) acc[i][j] += ka[i] * va[j];
    }
    __syncthreads();
  }

  float* p = part + ((size_t)bn * gridDim.y + blockIdx.y) * DD;
#pragma unroll
  for (int i = 0; i < 4; ++i) {
    *(float4*)&p[(k0 + i) * D + v0] =
        make_float4(acc[i][0], acc[i][1], acc[i][2], acc[i][3]);
  }
}

// ---------------------------------------------------------------------------
// Kernel 2: combine partials + memory term into Meff[bn][k][v]
//   Meff = sum_m gates[m]*sig[m]*memory[b,m,n] + (sum_m gates[m]*(1-sig[m])) * new_info
// grid = 64, block = 256
// ---------------------------------------------------------------------------
__global__ __launch_bounds__(256) void k2_combine(const float* __restrict__ part,
                                                  const float* __restrict__ memg,
                                                  const float* __restrict__ decay,
                                                  const float* __restrict__ gatew,
                                                  float* __restrict__ meff,
                                                  int nchunks) {
  const int t = threadIdx.x;
  const int bn = blockIdx.x;
  const int b = bn >> 4, n = bn & 15;

  float gw[M], df[M];
#pragma unroll
  for (int m = 0; m < M; ++m) { gw[m] = gatew[m]; df[m] = decay[m]; }
  const float mx = fmaxf(fmaxf(gw[0], gw[1]), fmaxf(gw[2], gw[3]));
  float e[M], esum = 0.f;
#pragma unroll
  for (int m = 0; m < M; ++m) { e[m] = expf(gw[m] - mx); esum += e[m]; }
  float w[M], c = 0.f;
#pragma unroll
  for (int m = 0; m < M; ++m) {
    const float g = e[m] / esum;
    const float sg = 1.f / (1.f + expf(-df[m]));
    w[m] = g * sg;
    c += g * (1.f - sg);
  }

  const float* pb = part + (size_t)bn * nchunks * DD;
#pragma unroll 4
  for (int i = 0; i < 16; ++i) {
    const int kv = t + i * 256;
    float ni = 0.f;
    for (int ch = 0; ch < nchunks; ++ch) ni += pb[(size_t)ch * DD + kv];
    float a = c * ni;
#pragma unroll
    for (int m = 0; m < M; ++m)
      a += w[m] * memg[(((size_t)b * M + m) * N + n) * DD + kv];
    meff[(size_t)bn * DD + kv] = a;
  }
}

// ---------------------------------------------------------------------------
// Kernel 3: out[b,s,n,v] = sum_k q[b,s,n,k] * Meff[bn][k][v]
// grid = (64, 64), block = 256; each block does 64 s-rows for one (b,n)
// ---------------------------------------------------------------------------
__global__ __launch_bounds__(256) void k3_out(const float* __restrict__ qg,
                                              const float* __restrict__ meff,
                                              float* __restrict__ outg) {
  __shared__ __align__(16) float Ms[64 * 64];   // Meff[k][v]
  __shared__ __align__(16) float qs[64 * 68];   // q[r][d], padded rows

  const int t = threadIdx.x;
  const int bn = blockIdx.x;
  const int b = bn >> 4, n = bn & 15;
  const int s0 = blockIdx.y * 64;

  const float* mp = meff + (size_t)bn * DD;
#pragma unroll
  for (int i = 0; i < 16; ++i) Ms[t + i * 256] = mp[t + i * 256];

  const size_t qbase = (size_t)b * SND + (size_t)s0 * ND + (size_t)n * D;
#pragma unroll
  for (int i = 0; i < 16; ++i) {
    const int idx = t + i * 256;
    const int r = idx >> 6, d = idx & 63;
    qs[r * 68 + d] = qg[qbase + (size_t)r * ND + d];
  }
  __syncthreads();

  const int r0 = (t >> 4) * 4;   // 4 s-rows
  const int v0 = (t & 15) * 4;   // 4 v cols
  float acc[4][4] = {};

#pragma unroll 4
  for (int k4 = 0; k4 < 16; ++k4) {
    float qa[4][4], ma[4][4];
#pragma unroll
    for (int i = 0; i < 4; ++i) {
      const float4 qv = *(const float4*)&qs[(r0 + i) * 68 + k4 * 4];
      qa[i][0] = qv.x; qa[i][1] = qv.y; qa[i][2] = qv.z; qa[i][3] = qv.w;
      const float4 mv = *(const float4*)&Ms[(k4 * 4 + i) * D + v0];
      ma[i][0] = mv.x; ma[i][1] = mv.y; ma[i][2] = mv.z; ma[i][3] = mv.w;
    }
#pragma unroll
    for (int r = 0; r < 4; ++r)
#pragma unroll
      for (int kk = 0; kk < 4; ++kk)
#pragma unroll
        for (int j = 0; j < 4; ++j) acc[r][j] += qa[r][kk] * ma[kk][j];
  }

#pragma unroll
  for (int i = 0; i < 4; ++i) {
    *(float4*)&outg[qbase + (size_t)(r0 + i) * ND + v0] =
        make_float4(acc[i][0], acc[i][1], acc[i][2], acc[i][3]);
  }
}

// ---------------------------------------------------------------------------
extern "C" void kernel_launch(void* const* d_in, const int* in_sizes, int n_in,
                              void* d_out, int out_size, void* d_ws, size_t ws_size,
                              hipStream_t stream) {
  const float* q     = (const float*)d_in[0];
  const float* k     = (const float*)d_in[1];
  const float* v     = (const float*)d_in[2];
  const float* memg  = (const float*)d_in[3];
  const float* decay = (const float*)d_in[4];
  const float* gatew = (const float*)d_in[5];
  float* out = (float*)d_out;

  float* meff = (float*)d_ws;                 // 64*4096 floats = 1 MB
  float* part = meff + (size_t)64 * DD;       // nchunks MB after that

  // pick partial-chunk count that fits in ws
  const size_t meff_bytes = (size_t)64 * DD * sizeof(float);
  const size_t avail = ws_size > meff_bytes ? ws_size - meff_bytes : 0;
  int nchunks = 16;
  while (nchunks > 1 && (size_t)nchunks * 64 * DD * sizeof(float) > avail)
    nchunks >>= 1;
  const int spb = S / nchunks;

  hipLaunchKernelGGL(k1_partials, dim3(64, nchunks), dim3(256), 0, stream,
                     k, v, part, spb);
  hipLaunchKernelGGL(k2_combine, dim3(64), dim3(256), 0, stream,
                     part, memg, decay, gatew, meff, nchunks);
  hipLaunchKernelGGL(k3_out, dim3(64, 64), dim3(256), 0, stream,
                     q, meff, out);
}

// Round 2
// 89.408 us; speedup vs baseline: 1.7547x; 1.7547x over previous
//
#include <hip/hip_runtime.h>
#include <math.h>

// Problem constants
constexpr int B = 4, S = 4096, N = 16, D = 64, M = 4;
constexpr int SND = S * N * D;      // 4,194,304 (b stride for q/k/v)
constexpr int ND  = N * D;          // 1024 (s stride)
constexpr int DD  = D * D;          // 4096

// ---------------------------------------------------------------------------
// Kernel 1: partial outer-product accumulation
//   part[bn][chunk][k][v] = sum_{s in chunk} k[b,s,n,k] * v[b,s,n,v]
// grid = (64, nchunks), block = 256. Double-buffered LDS, reg-prefetch.
// ---------------------------------------------------------------------------
__global__ __launch_bounds__(256) void k1_partials(const float* __restrict__ kg,
                                                   const float* __restrict__ vg,
                                                   float* __restrict__ part,
                                                   int spb) {
  __shared__ __align__(16) float kb[2][16 * 64];
  __shared__ __align__(16) float vb[2][16 * 64];

  const int t = threadIdx.x;
  const int bn = blockIdx.x;
  const int b = bn >> 4, n = bn & 15;
  const size_t base = (size_t)b * SND + (size_t)n * D;
  const int s0 = blockIdx.y * spb;

  const int row = t >> 4;          // 0..15  (staging row)
  const int d4  = (t & 15) * 4;    // 0..60  (staging col, float4)
  const int k0  = (t >> 4) * 4;    // compute tile: k rows
  const int v0  = (t & 15) * 4;    // compute tile: v cols

  float acc[4][4] = {};

  const float* kp = kg + base + (size_t)(s0 + row) * ND + d4;
  const float* vp = vg + base + (size_t)(s0 + row) * ND + d4;
  float4 kl = *(const float4*)kp;
  float4 vl = *(const float4*)vp;

  const int niter = spb >> 4;
  for (int it = 0; it < niter; ++it) {
    const int cur = it & 1;
    *(float4*)&kb[cur][row * 64 + d4] = kl;
    *(float4*)&vb[cur][row * 64 + d4] = vl;
    if (it + 1 < niter) {               // prefetch next stage into regs
      kp += 16 * ND; vp += 16 * ND;
      kl = *(const float4*)kp;
      vl = *(const float4*)vp;
    }
    __syncthreads();                    // buf[cur] visible; prev-parity reads done
#pragma unroll
    for (int ss = 0; ss < 16; ++ss) {
      const float4 kk4 = *(const float4*)&kb[cur][ss * 64 + k0];
      const float4 vv4 = *(const float4*)&vb[cur][ss * 64 + v0];
      const float ka[4] = {kk4.x, kk4.y, kk4.z, kk4.w};
      const float va[4] = {vv4.x, vv4.y, vv4.z, vv4.w};
#pragma unroll
      for (int i = 0; i < 4; ++i)
#pragma unroll
        for (int j = 0; j < 4; ++j) acc[i][j] += ka[i] * va[j];
    }
  }

  float* p = part + ((size_t)bn * gridDim.y + blockIdx.y) * DD;
#pragma unroll
  for (int i = 0; i < 4; ++i) {
    *(float4*)&p[(k0 + i) * D + v0] =
        make_float4(acc[i][0], acc[i][1], acc[i][2], acc[i][3]);
  }
}

// ---------------------------------------------------------------------------
// Kernel 2: combine partials + memory term into Meff[bn][k][v]
//   Meff = sum_m gates[m]*sig[m]*memory[b,m,n] + (sum_m gates[m]*(1-sig[m])) * new_info
// grid = (64, 16), block = 256 — one thread per kv element (fully parallel)
// ---------------------------------------------------------------------------
__global__ __launch_bounds__(256) void k2_combine(const float* __restrict__ part,
                                                  const float* __restrict__ memg,
                                                  const float* __restrict__ decay,
                                                  const float* __restrict__ gatew,
                                                  float* __restrict__ meff,
                                                  int nchunks) {
  const int t = threadIdx.x;
  const int bn = blockIdx.x;
  const int b = bn >> 4, n = bn & 15;
  const int kv = blockIdx.y * 256 + t;

  float gw[M], df[M];
#pragma unroll
  for (int m = 0; m < M; ++m) { gw[m] = gatew[m]; df[m] = decay[m]; }
  const float mx = fmaxf(fmaxf(gw[0], gw[1]), fmaxf(gw[2], gw[3]));
  float e[M], esum = 0.f;
#pragma unroll
  for (int m = 0; m < M; ++m) { e[m] = expf(gw[m] - mx); esum += e[m]; }
  float w[M], c = 0.f;
#pragma unroll
  for (int m = 0; m < M; ++m) {
    const float g = e[m] / esum;
    const float sg = 1.f / (1.f + expf(-df[m]));
    w[m] = g * sg;
    c += g * (1.f - sg);
  }

  const float* pb = part + (size_t)bn * nchunks * DD + kv;
  float ni = 0.f;
  for (int ch = 0; ch < nchunks; ++ch) ni += pb[(size_t)ch * DD];
  float a = c * ni;
#pragma unroll
  for (int m = 0; m < M; ++m)
    a += w[m] * memg[(((size_t)b * M + m) * N + n) * DD + kv];
  meff[(size_t)bn * DD + kv] = a;
}

// ---------------------------------------------------------------------------
// Kernel 3: out[b,s,n,v] = sum_k q[b,s,n,k] * Meff[bn][k][v]
// grid = (64, 64), block = 256; each block does 64 s-rows for one (b,n)
// ---------------------------------------------------------------------------
__global__ __launch_bounds__(256) void k3_out(const float* __restrict__ qg,
                                              const float* __restrict__ meff,
                                              float* __restrict__ outg) {
  __shared__ __align__(16) float Ms[64 * 64];   // Meff[k][v]
  __shared__ __align__(16) float qs[64 * 68];   // q[r][d], padded rows

  const int t = threadIdx.x;
  const int bn = blockIdx.x;
  const int b = bn >> 4, n = bn & 15;
  const int s0 = blockIdx.y * 64;

  const float4* mp4 = (const float4*)(meff + (size_t)bn * DD);
#pragma unroll
  for (int i = 0; i < 4; ++i) ((float4*)Ms)[t + i * 256] = mp4[t + i * 256];

  const size_t qbase = (size_t)b * SND + (size_t)s0 * ND + (size_t)n * D;
#pragma unroll
  for (int i = 0; i < 4; ++i) {
    const int idx = t + i * 256;       // float4 index: 64 rows x 16 per row
    const int r = idx >> 4, c4 = (idx & 15) * 4;
    *(float4*)&qs[r * 68 + c4] = *(const float4*)(qg + qbase + (size_t)r * ND + c4);
  }
  __syncthreads();

  const int r0 = (t >> 4) * 4;   // 4 s-rows
  const int v0 = (t & 15) * 4;   // 4 v cols
  float acc[4][4] = {};

#pragma unroll 4
  for (int k4 = 0; k4 < 16; ++k4) {
    float qa[4][4], ma[4][4];
#pragma unroll
    for (int i = 0; i < 4; ++i) {
      const float4 qv = *(const float4*)&qs[(r0 + i) * 68 + k4 * 4];
      qa[i][0] = qv.x; qa[i][1] = qv.y; qa[i][2] = qv.z; qa[i][3] = qv.w;
      const float4 mv = *(const float4*)&Ms[(k4 * 4 + i) * D + v0];
      ma[i][0] = mv.x; ma[i][1] = mv.y; ma[i][2] = mv.z; ma[i][3] = mv.w;
    }
#pragma unroll
    for (int r = 0; r < 4; ++r)
#pragma unroll
      for (int kk = 0; kk < 4; ++kk)
#pragma unroll
        for (int j = 0; j < 4; ++j) acc[r][j] += qa[r][kk] * ma[kk][j];
  }

#pragma unroll
  for (int i = 0; i < 4; ++i) {
    *(float4*)&outg[qbase + (size_t)(r0 + i) * ND + v0] =
        make_float4(acc[i][0], acc[i][1], acc[i][2], acc[i][3]);
  }
}

// ---------------------------------------------------------------------------
extern "C" void kernel_launch(void* const* d_in, const int* in_sizes, int n_in,
                              void* d_out, int out_size, void* d_ws, size_t ws_size,
                              hipStream_t stream) {
  const float* q     = (const float*)d_in[0];
  const float* k     = (const float*)d_in[1];
  const float* v     = (const float*)d_in[2];
  const float* memg  = (const float*)d_in[3];
  const float* decay = (const float*)d_in[4];
  const float* gatew = (const float*)d_in[5];
  float* out = (float*)d_out;

  float* meff = (float*)d_ws;                 // 64*4096 floats = 1 MB
  float* part = meff + (size_t)64 * DD;       // nchunks MB after that

  // pick partial-chunk count that fits in ws
  const size_t meff_bytes = (size_t)64 * DD * sizeof(float);
  const size_t avail = ws_size > meff_bytes ? ws_size - meff_bytes : 0;
  int nchunks = 16;
  while (nchunks > 1 && (size_t)nchunks * 64 * DD * sizeof(float) > avail)
    nchunks >>= 1;
  const int spb = S / nchunks;

  hipLaunchKernelGGL(k1_partials, dim3(64, nchunks), dim3(256), 0, stream,
                     k, v, part, spb);
  hipLaunchKernelGGL(k2_combine, dim3(64, 16), dim3(256), 0, stream,
                     part, memg, decay, gatew, meff, nchunks);
  hipLaunchKernelGGL(k3_out, dim3(64, 64), dim3(256), 0, stream,
                     q, meff, out);
}